// Round 1
// baseline (6666.679 us; speedup 1.0000x reference)
//
#include <hip/hip_runtime.h>

#define ATOMF 82
#define EDGE_DIM 6
#define HIDDEN 10

__device__ __forceinline__ float lrelu(float x) { return x > 0.f ? x : 0.1f * x; }

// h[node] = lrelu(vertex[node] @ W)   W: [82][10] row-major
__global__ void embed_kernel(const float* __restrict__ vertex,
                             const float* __restrict__ W,
                             float* __restrict__ h, int n_nodes) {
    __shared__ float w[ATOMF * HIDDEN];
    for (int i = threadIdx.x; i < ATOMF * HIDDEN; i += blockDim.x) w[i] = W[i];
    __syncthreads();
    int node = blockIdx.x * blockDim.x + threadIdx.x;
    if (node >= n_nodes) return;
    const float* v = vertex + (long)node * ATOMF;
    float acc[HIDDEN];
#pragma unroll
    for (int j = 0; j < HIDDEN; j++) acc[j] = 0.f;
#pragma unroll 2
    for (int k = 0; k < ATOMF; k++) {
        float x = v[k];
#pragma unroll
        for (int j = 0; j < HIDDEN; j++) acc[j] += x * w[k * HIDDEN + j];
    }
    float* out = h + (long)node * HIDDEN;
#pragma unroll
    for (int j = 0; j < HIDDEN; j++) out[j] = lrelu(acc[j]);
}

// per-edge: msg = lrelu(concat(h[src], edge_feat) @ GW); atomicAdd into agg[dst]
// GW: [16][10] row-major
__global__ void edge_kernel(const float* __restrict__ h,
                            const float* __restrict__ ef,
                            const int* __restrict__ src,
                            const int* __restrict__ dst,
                            const float* __restrict__ GW,
                            float* __restrict__ agg, long n_edges) {
    __shared__ float w[(HIDDEN + EDGE_DIM) * HIDDEN];
    for (int i = threadIdx.x; i < (HIDDEN + EDGE_DIM) * HIDDEN; i += blockDim.x) w[i] = GW[i];
    __syncthreads();
    long e = (long)blockIdx.x * blockDim.x + threadIdx.x;
    if (e >= n_edges) return;
    int s = src[e];
    int d = dst[e];
    float in[HIDDEN + EDGE_DIM];
    const float2* hp = (const float2*)(h + (long)s * HIDDEN);  // 40B rows, 8B aligned
#pragma unroll
    for (int k = 0; k < 5; k++) { float2 t = hp[k]; in[2 * k] = t.x; in[2 * k + 1] = t.y; }
    const float2* ep = (const float2*)(ef + e * (long)EDGE_DIM);  // 24B rows, 8B aligned
#pragma unroll
    for (int k = 0; k < 3; k++) { float2 t = ep[k]; in[HIDDEN + 2 * k] = t.x; in[HIDDEN + 2 * k + 1] = t.y; }
    float m[HIDDEN];
#pragma unroll
    for (int j = 0; j < HIDDEN; j++) m[j] = 0.f;
#pragma unroll
    for (int k = 0; k < HIDDEN + EDGE_DIM; k++) {
        float x = in[k];
#pragma unroll
        for (int j = 0; j < HIDDEN; j++) m[j] += x * w[k * HIDDEN + j];
    }
    float* ap = agg + (long)d * HIDDEN;
#pragma unroll
    for (int j = 0; j < HIDDEN; j++) atomicAdd(ap + j, lrelu(m[j]));
}

// h_out[node] = lrelu(concat(h[node], agg[node]) @ UW)   UW: [20][10]
// safe in-place on h (thread touches only its own row)
__global__ void update_kernel(const float* __restrict__ h,
                              const float* __restrict__ agg,
                              const float* __restrict__ UW,
                              float* __restrict__ h_out, int n_nodes) {
    __shared__ float w[2 * HIDDEN * HIDDEN];
    for (int i = threadIdx.x; i < 2 * HIDDEN * HIDDEN; i += blockDim.x) w[i] = UW[i];
    __syncthreads();
    int node = blockIdx.x * blockDim.x + threadIdx.x;
    if (node >= n_nodes) return;
    float in[2 * HIDDEN];
    const float2* hp = (const float2*)(h + (long)node * HIDDEN);
#pragma unroll
    for (int k = 0; k < 5; k++) { float2 t = hp[k]; in[2 * k] = t.x; in[2 * k + 1] = t.y; }
    const float2* ap = (const float2*)(agg + (long)node * HIDDEN);
#pragma unroll
    for (int k = 0; k < 5; k++) { float2 t = ap[k]; in[HIDDEN + 2 * k] = t.x; in[HIDDEN + 2 * k + 1] = t.y; }
    float acc[HIDDEN];
#pragma unroll
    for (int j = 0; j < HIDDEN; j++) acc[j] = 0.f;
#pragma unroll
    for (int k = 0; k < 2 * HIDDEN; k++) {
        float x = in[k];
#pragma unroll
        for (int j = 0; j < HIDDEN; j++) acc[j] += x * w[k * HIDDEN + j];
    }
    float* out = h_out + (long)node * HIDDEN;
#pragma unroll
    for (int j = 0; j < HIDDEN; j++) out[j] = lrelu(acc[j]);
}

extern "C" void kernel_launch(void* const* d_in, const int* in_sizes, int n_in,
                              void* d_out, int out_size, void* d_ws, size_t ws_size,
                              hipStream_t stream) {
    const float* vertex    = (const float*)d_in[0];
    const float* edge_feat = (const float*)d_in[1];
    const int*   src       = (const int*)d_in[2];
    const int*   dst       = (const int*)d_in[3];
    const float* w_init    = (const float*)d_in[4];
    const float* gw        = (const float*)d_in[5];
    const float* uw        = (const float*)d_in[6];

    const int  n_nodes = in_sizes[0] / ATOMF;
    const long n_edges = (long)in_sizes[2];
    float* out = (float*)d_out;

    float* h_tmp = (float*)d_ws;                              // n_nodes*HIDDEN floats
    float* agg   = h_tmp + (size_t)n_nodes * HIDDEN;          // n_nodes*HIDDEN floats
    const size_t agg_bytes = (size_t)n_nodes * HIDDEN * sizeof(float);

    const int TB = 256;
    const int node_blocks = (n_nodes + TB - 1) / TB;
    const int edge_blocks = (int)((n_edges + TB - 1) / TB);

    embed_kernel<<<node_blocks, TB, 0, stream>>>(vertex, w_init, h_tmp, n_nodes);

    // layer 1: h_tmp -> out
    hipMemsetAsync(agg, 0, agg_bytes, stream);
    edge_kernel<<<edge_blocks, TB, 0, stream>>>(h_tmp, edge_feat, src, dst, gw, agg, n_edges);
    update_kernel<<<node_blocks, TB, 0, stream>>>(h_tmp, agg, uw, out, n_nodes);

    // layer 2: out -> out (in-place safe)
    hipMemsetAsync(agg, 0, agg_bytes, stream);
    edge_kernel<<<edge_blocks, TB, 0, stream>>>(out, edge_feat, src, dst, gw, agg, n_edges);
    update_kernel<<<node_blocks, TB, 0, stream>>>(out, agg, uw, out, n_nodes);
}

// Round 2
// 1907.945 us; speedup vs baseline: 3.4942x; 3.4942x over previous
//
#include <hip/hip_runtime.h>

#define ATOMF 82
#define EDGE_DIM 6
#define HIDDEN 10

__device__ __forceinline__ float lrelu(float x) { return x > 0.f ? x : 0.1f * x; }

// h[node] = lrelu(vertex[node] @ W)   W: [82][10] row-major
__global__ void embed_kernel(const float* __restrict__ vertex,
                             const float* __restrict__ W,
                             float* __restrict__ h, int n_nodes) {
    __shared__ float w[ATOMF * HIDDEN];
    for (int i = threadIdx.x; i < ATOMF * HIDDEN; i += blockDim.x) w[i] = W[i];
    __syncthreads();
    int node = blockIdx.x * blockDim.x + threadIdx.x;
    if (node >= n_nodes) return;
    const float* v = vertex + (long)node * ATOMF;
    float acc[HIDDEN];
#pragma unroll
    for (int j = 0; j < HIDDEN; j++) acc[j] = 0.f;
#pragma unroll 2
    for (int k = 0; k < ATOMF; k++) {
        float x = v[k];
#pragma unroll
        for (int j = 0; j < HIDDEN; j++) acc[j] += x * w[k * HIDDEN + j];
    }
    float* out = h + (long)node * HIDDEN;
#pragma unroll
    for (int j = 0; j < HIDDEN; j++) out[j] = lrelu(acc[j]);
}

// one pass: per-edge position within its dst bucket + final per-node degree
__global__ void count_pos_kernel(const int* __restrict__ dst, int* __restrict__ counts,
                                 unsigned short* __restrict__ pos, long n_edges) {
    long e = (long)blockIdx.x * blockDim.x + threadIdx.x;
    if (e >= n_edges) return;
    pos[e] = (unsigned short)atomicAdd(&counts[dst[e]], 1);
}

// single-block exclusive prefix sum: counts[0..n-1] -> offsets[0..n]
__global__ __launch_bounds__(1024) void scan_kernel(const int* __restrict__ counts,
                                                    int* __restrict__ offsets, int n) {
    __shared__ int wsum[16];
    __shared__ int carry_s;
    int lane = threadIdx.x & 63, wid = threadIdx.x >> 6;
    if (threadIdx.x == 0) carry_s = 0;
    __syncthreads();
    for (int base = 0; base < n; base += 1024) {
        int i = base + threadIdx.x;
        int v = (i < n) ? counts[i] : 0;
        int incl = v;
#pragma unroll
        for (int off = 1; off < 64; off <<= 1) {
            int t = __shfl_up(incl, off, 64);
            if (lane >= off) incl += t;
        }
        if (lane == 63) wsum[wid] = incl;
        __syncthreads();
        if (wid == 0 && lane < 16) {
            int wv = wsum[lane];
            int wincl = wv;
#pragma unroll
            for (int off = 1; off < 16; off <<= 1) {
                int t = __shfl_up(wincl, off, 64);
                if (lane >= off) wincl += t;
            }
            wsum[lane] = wincl - wv;  // exclusive prefix of wave totals
        }
        __syncthreads();
        int carry = carry_s;
        if (i < n) offsets[i] = carry + wsum[wid] + (incl - v);
        __syncthreads();
        if (threadIdx.x == 1023) carry_s = carry + wsum[15] + incl;  // + full tile sum
        __syncthreads();
    }
    if (threadIdx.x == 0) offsets[n] = carry_s;
}

// eid_sorted[offsets[dst[e]] + pos[e]] = e
__global__ void scatter_kernel(const int* __restrict__ dst, const unsigned short* __restrict__ pos,
                               const int* __restrict__ offsets, int* __restrict__ eid, long n_edges) {
    long e = (long)blockIdx.x * blockDim.x + threadIdx.x;
    if (e >= n_edges) return;
    eid[offsets[dst[e]] + (int)pos[e]] = (int)e;
}

// one wave per dst node: gather incoming messages (atomic-free), fuse update GEMV
__global__ __launch_bounds__(256) void gather_update_kernel(
    const float* __restrict__ h_in, const float* __restrict__ ef,
    const int* __restrict__ src, const int* __restrict__ eid,
    const int* __restrict__ offsets,
    const float* __restrict__ GW, const float* __restrict__ UW,
    float* __restrict__ h_out, int n_nodes) {
    __shared__ float gw[(HIDDEN + EDGE_DIM) * HIDDEN];
    __shared__ float uw[2 * HIDDEN * HIDDEN];
    for (int i = threadIdx.x; i < (HIDDEN + EDGE_DIM) * HIDDEN; i += 256) gw[i] = GW[i];
    for (int i = threadIdx.x; i < 2 * HIDDEN * HIDDEN; i += 256) uw[i] = UW[i];
    __syncthreads();
    int wid = threadIdx.x >> 6, lane = threadIdx.x & 63;
    int node = blockIdx.x * 4 + wid;
    if (node >= n_nodes) return;
    int off0 = offsets[node], off1 = offsets[node + 1];
    float acc[HIDDEN];
#pragma unroll
    for (int j = 0; j < HIDDEN; j++) acc[j] = 0.f;
    for (int p = off0 + lane; p < off1; p += 64) {
        int e = eid[p];
        int s = src[e];
        float in[HIDDEN + EDGE_DIM];
        const float2* hp = (const float2*)(h_in + (long)s * HIDDEN);
#pragma unroll
        for (int k = 0; k < 5; k++) { float2 t = hp[k]; in[2 * k] = t.x; in[2 * k + 1] = t.y; }
        const float2* ep = (const float2*)(ef + (long)e * EDGE_DIM);
#pragma unroll
        for (int k = 0; k < 3; k++) { float2 t = ep[k]; in[HIDDEN + 2 * k] = t.x; in[HIDDEN + 2 * k + 1] = t.y; }
        float m[HIDDEN];
#pragma unroll
        for (int j = 0; j < HIDDEN; j++) m[j] = 0.f;
#pragma unroll
        for (int k = 0; k < HIDDEN + EDGE_DIM; k++) {
            float x = in[k];
#pragma unroll
            for (int j = 0; j < HIDDEN; j++) m[j] += x * gw[k * HIDDEN + j];
        }
#pragma unroll
        for (int j = 0; j < HIDDEN; j++) acc[j] += lrelu(m[j]);
    }
    // wave-reduce the 10 accumulators to lane 0
#pragma unroll
    for (int j = 0; j < HIDDEN; j++) {
#pragma unroll
        for (int d = 32; d > 0; d >>= 1) acc[j] += __shfl_down(acc[j], d, 64);
    }
    if (lane == 0) {
        float in[2 * HIDDEN];
        const float2* hp = (const float2*)(h_in + (long)node * HIDDEN);
#pragma unroll
        for (int k = 0; k < 5; k++) { float2 t = hp[k]; in[2 * k] = t.x; in[2 * k + 1] = t.y; }
#pragma unroll
        for (int j = 0; j < HIDDEN; j++) in[HIDDEN + j] = acc[j];
        float o[HIDDEN];
#pragma unroll
        for (int j = 0; j < HIDDEN; j++) o[j] = 0.f;
#pragma unroll
        for (int k = 0; k < 2 * HIDDEN; k++) {
            float x = in[k];
#pragma unroll
            for (int j = 0; j < HIDDEN; j++) o[j] += x * uw[k * HIDDEN + j];
        }
        float* outp = h_out + (long)node * HIDDEN;
#pragma unroll
        for (int j = 0; j < HIDDEN; j++) outp[j] = lrelu(o[j]);
    }
}

extern "C" void kernel_launch(void* const* d_in, const int* in_sizes, int n_in,
                              void* d_out, int out_size, void* d_ws, size_t ws_size,
                              hipStream_t stream) {
    const float* vertex    = (const float*)d_in[0];
    const float* edge_feat = (const float*)d_in[1];
    const int*   src       = (const int*)d_in[2];
    const int*   dst       = (const int*)d_in[3];
    const float* w_init    = (const float*)d_in[4];
    const float* gw        = (const float*)d_in[5];
    const float* uw        = (const float*)d_in[6];

    const int  n_nodes = in_sizes[0] / ATOMF;
    const long n_edges = (long)in_sizes[2];
    float* out = (float*)d_out;

    // workspace layout (256B-aligned sections)
    char* ws = (char*)d_ws;
    size_t o = 0;
    auto alloc = [&](size_t bytes) { char* p = ws + o; o = (o + bytes + 255) & ~(size_t)255; return p; };
    float*          h0      = (float*)alloc((size_t)n_nodes * HIDDEN * sizeof(float));
    float*          h1      = (float*)alloc((size_t)n_nodes * HIDDEN * sizeof(float));
    int*            counts  = (int*)alloc((size_t)(n_nodes + 1) * sizeof(int));
    int*            offsets = (int*)alloc((size_t)(n_nodes + 1) * sizeof(int));
    unsigned short* pos     = (unsigned short*)alloc((size_t)n_edges * sizeof(unsigned short));
    int*            eid     = (int*)alloc((size_t)n_edges * sizeof(int));
    (void)ws_size;

    const int TB = 256;
    const int node_blocks = (n_nodes + TB - 1) / TB;
    const int edge_blocks = (int)((n_edges + TB - 1) / TB);
    const int gu_blocks   = (n_nodes + 3) / 4;

    // CSR build (once; reused by both layers)
    hipMemsetAsync(counts, 0, (size_t)(n_nodes + 1) * sizeof(int), stream);
    count_pos_kernel<<<edge_blocks, TB, 0, stream>>>(dst, counts, pos, n_edges);
    scan_kernel<<<1, 1024, 0, stream>>>(counts, offsets, n_nodes);
    scatter_kernel<<<edge_blocks, TB, 0, stream>>>(dst, pos, offsets, eid, n_edges);

    embed_kernel<<<node_blocks, TB, 0, stream>>>(vertex, w_init, h0, n_nodes);

    // layer 1: h0 -> h1
    gather_update_kernel<<<gu_blocks, TB, 0, stream>>>(h0, edge_feat, src, eid, offsets,
                                                       gw, uw, h1, n_nodes);
    // layer 2: h1 -> out
    gather_update_kernel<<<gu_blocks, TB, 0, stream>>>(h1, edge_feat, src, eid, offsets,
                                                       gw, uw, out, n_nodes);
}

// Round 3
// 1400.857 us; speedup vs baseline: 4.7590x; 1.3620x over previous
//
#include <hip/hip_runtime.h>

#define ATOMF 82
#define EDGE_DIM 6
#define HIDDEN 10

__device__ __forceinline__ float lrelu(float x) { return x > 0.f ? x : 0.1f * x; }

__device__ __forceinline__ unsigned short f2bf(float f) {
    unsigned int u = __float_as_uint(f);
    unsigned int r = (u + 0x7fffu + ((u >> 16) & 1u)) >> 16;  // RNE
    return (unsigned short)r;
}
__device__ __forceinline__ float bf2f(unsigned int b) {
    return __uint_as_float(b << 16);
}

// h[node] = lrelu(vertex[node] @ W)   W: [82][10] row-major
__global__ void embed_kernel(const float* __restrict__ vertex,
                             const float* __restrict__ W,
                             float* __restrict__ h, int n_nodes) {
    __shared__ float w[ATOMF * HIDDEN];
    for (int i = threadIdx.x; i < ATOMF * HIDDEN; i += blockDim.x) w[i] = W[i];
    __syncthreads();
    int node = blockIdx.x * blockDim.x + threadIdx.x;
    if (node >= n_nodes) return;
    const float* v = vertex + (long)node * ATOMF;
    float acc[HIDDEN];
#pragma unroll
    for (int j = 0; j < HIDDEN; j++) acc[j] = 0.f;
#pragma unroll 2
    for (int k = 0; k < ATOMF; k++) {
        float x = v[k];
#pragma unroll
        for (int j = 0; j < HIDDEN; j++) acc[j] += x * w[k * HIDDEN + j];
    }
    float* out = h + (long)node * HIDDEN;
#pragma unroll
    for (int j = 0; j < HIDDEN; j++) out[j] = lrelu(acc[j]);
}

// per-edge position within its dst bucket + per-node degree (int atomics, L2-resident)
__global__ void count_pos_kernel(const int* __restrict__ dst, int* __restrict__ counts,
                                 unsigned short* __restrict__ pos, long n_edges) {
    long e = (long)blockIdx.x * blockDim.x + threadIdx.x;
    if (e >= n_edges) return;
    pos[e] = (unsigned short)atomicAdd(&counts[dst[e]], 1);
}

// single-block exclusive prefix sum: counts[0..n-1] -> offsets[0..n]
__global__ __launch_bounds__(1024) void scan_kernel(const int* __restrict__ counts,
                                                    int* __restrict__ offsets, int n) {
    __shared__ int wsum[16];
    __shared__ int carry_s;
    int lane = threadIdx.x & 63, wid = threadIdx.x >> 6;
    if (threadIdx.x == 0) carry_s = 0;
    __syncthreads();
    for (int base = 0; base < n; base += 1024) {
        int i = base + threadIdx.x;
        int v = (i < n) ? counts[i] : 0;
        int incl = v;
#pragma unroll
        for (int off = 1; off < 64; off <<= 1) {
            int t = __shfl_up(incl, off, 64);
            if (lane >= off) incl += t;
        }
        if (lane == 63) wsum[wid] = incl;
        __syncthreads();
        if (wid == 0 && lane < 16) {
            int wv = wsum[lane];
            int wincl = wv;
#pragma unroll
            for (int off = 1; off < 16; off <<= 1) {
                int t = __shfl_up(wincl, off, 64);
                if (lane >= off) wincl += t;
            }
            wsum[lane] = wincl - wv;  // exclusive prefix of wave totals
        }
        __syncthreads();
        int carry = carry_s;
        if (i < n) offsets[i] = carry + wsum[wid] + (incl - v);
        __syncthreads();
        if (threadIdx.x == 1023) carry_s = carry + wsum[15] + incl;
        __syncthreads();
    }
    if (threadIdx.x == 0) offsets[n] = carry_s;
}

// eid[offsets[dst[e]] + pos[e]] = e
__global__ void scatter_kernel(const int* __restrict__ dst, const unsigned short* __restrict__ pos,
                               const int* __restrict__ offsets, int* __restrict__ eid, long n_edges) {
    long e = (long)blockIdx.x * blockDim.x + threadIdx.x;
    if (e >= n_edges) return;
    eid[offsets[dst[e]] + (int)pos[e]] = (int)e;
}

// one-time: materialize edge data in CSR order (random reads paid ONCE)
// src_perm[p] = src[eid[p]]; ef_perm[p] = bf16(ef[eid[p]])
__global__ void permute_kernel(const int* __restrict__ eid, const int* __restrict__ src,
                               const float* __restrict__ ef,
                               int* __restrict__ src_perm, unsigned short* __restrict__ ef_perm,
                               long n_edges) {
    long p = (long)blockIdx.x * blockDim.x + threadIdx.x;
    if (p >= n_edges) return;
    int e = eid[p];
    src_perm[p] = src[e];
    const float2* er = (const float2*)(ef + (long)e * EDGE_DIM);
    float2 a = er[0], b = er[1], c = er[2];
    unsigned int* ep = (unsigned int*)(ef_perm + p * (long)EDGE_DIM);
    ep[0] = (unsigned int)f2bf(a.x) | ((unsigned int)f2bf(a.y) << 16);
    ep[1] = (unsigned int)f2bf(b.x) | ((unsigned int)f2bf(b.y) << 16);
    ep[2] = (unsigned int)f2bf(c.x) | ((unsigned int)f2bf(c.y) << 16);
}

// 16 lanes per dst node: stream CSR-ordered edges, gather h (L2-resident), fuse update GEMV
__global__ __launch_bounds__(256) void gather_update_kernel(
    const float* __restrict__ h_in, const unsigned short* __restrict__ ef_perm,
    const int* __restrict__ src_perm, const int* __restrict__ offsets,
    const float* __restrict__ GW, const float* __restrict__ UW,
    float* __restrict__ h_out, int n_nodes) {
    __shared__ float gw[(HIDDEN + EDGE_DIM) * HIDDEN];
    __shared__ float uw[2 * HIDDEN * HIDDEN];
    for (int i = threadIdx.x; i < (HIDDEN + EDGE_DIM) * HIDDEN; i += 256) gw[i] = GW[i];
    for (int i = threadIdx.x; i < 2 * HIDDEN * HIDDEN; i += 256) uw[i] = UW[i];
    __syncthreads();
    int group = threadIdx.x >> 4;  // 16 nodes per block
    int sub = threadIdx.x & 15;
    int node = blockIdx.x * 16 + group;
    if (node >= n_nodes) return;
    int off0 = offsets[node], off1 = offsets[node + 1];
    float acc[HIDDEN];
#pragma unroll
    for (int j = 0; j < HIDDEN; j++) acc[j] = 0.f;
    for (int p = off0 + sub; p < off1; p += 16) {
        int s = src_perm[p];
        float in[HIDDEN + EDGE_DIM];
        const float2* hp = (const float2*)(h_in + (long)s * HIDDEN);
#pragma unroll
        for (int k = 0; k < 5; k++) { float2 t = hp[k]; in[2 * k] = t.x; in[2 * k + 1] = t.y; }
        const unsigned int* ep = (const unsigned int*)(ef_perm + (long)p * EDGE_DIM);
        unsigned int u0 = ep[0], u1 = ep[1], u2 = ep[2];
        in[10] = bf2f(u0 & 0xffffu); in[11] = bf2f(u0 >> 16);
        in[12] = bf2f(u1 & 0xffffu); in[13] = bf2f(u1 >> 16);
        in[14] = bf2f(u2 & 0xffffu); in[15] = bf2f(u2 >> 16);
        float m[HIDDEN];
#pragma unroll
        for (int j = 0; j < HIDDEN; j++) m[j] = 0.f;
#pragma unroll
        for (int k = 0; k < HIDDEN + EDGE_DIM; k++) {
            float x = in[k];
#pragma unroll
            for (int j = 0; j < HIDDEN; j++) m[j] += x * gw[k * HIDDEN + j];
        }
#pragma unroll
        for (int j = 0; j < HIDDEN; j++) acc[j] += lrelu(m[j]);
    }
    // reduce over the 16-lane group
#pragma unroll
    for (int j = 0; j < HIDDEN; j++) {
#pragma unroll
        for (int d = 8; d > 0; d >>= 1) acc[j] += __shfl_down(acc[j], d, 16);
    }
    if (sub == 0) {
        float in[2 * HIDDEN];
        const float2* hp = (const float2*)(h_in + (long)node * HIDDEN);
#pragma unroll
        for (int k = 0; k < 5; k++) { float2 t = hp[k]; in[2 * k] = t.x; in[2 * k + 1] = t.y; }
#pragma unroll
        for (int j = 0; j < HIDDEN; j++) in[HIDDEN + j] = acc[j];
        float o[HIDDEN];
#pragma unroll
        for (int j = 0; j < HIDDEN; j++) o[j] = 0.f;
#pragma unroll
        for (int k = 0; k < 2 * HIDDEN; k++) {
            float x = in[k];
#pragma unroll
            for (int j = 0; j < HIDDEN; j++) o[j] += x * uw[k * HIDDEN + j];
        }
        float* outp = h_out + (long)node * HIDDEN;
#pragma unroll
        for (int j = 0; j < HIDDEN; j++) outp[j] = lrelu(o[j]);
    }
}

extern "C" void kernel_launch(void* const* d_in, const int* in_sizes, int n_in,
                              void* d_out, int out_size, void* d_ws, size_t ws_size,
                              hipStream_t stream) {
    const float* vertex    = (const float*)d_in[0];
    const float* edge_feat = (const float*)d_in[1];
    const int*   src       = (const int*)d_in[2];
    const int*   dst       = (const int*)d_in[3];
    const float* w_init    = (const float*)d_in[4];
    const float* gw        = (const float*)d_in[5];
    const float* uw        = (const float*)d_in[6];

    const int  n_nodes = in_sizes[0] / ATOMF;
    const long n_edges = (long)in_sizes[2];
    float* out = (float*)d_out;

    // workspace layout (256B-aligned). pos/eid region is reused for h0/h1
    // after the CSR build completes (embed runs after permute).
    char* ws = (char*)d_ws;
    size_t o = 0;
    auto alloc = [&](size_t bytes) { char* p = ws + o; o = (o + bytes + 255) & ~(size_t)255; return p; };
    int*            counts   = (int*)alloc((size_t)(n_nodes + 1) * sizeof(int));
    int*            offsets  = (int*)alloc((size_t)(n_nodes + 1) * sizeof(int));
    int*            src_perm = (int*)alloc((size_t)n_edges * sizeof(int));
    unsigned short* ef_perm  = (unsigned short*)alloc((size_t)n_edges * EDGE_DIM * sizeof(unsigned short));
    char*           overlay  = alloc((size_t)n_edges * (sizeof(unsigned short) + sizeof(int)));
    unsigned short* pos      = (unsigned short*)overlay;
    int*            eid      = (int*)(overlay + (((size_t)n_edges * sizeof(unsigned short) + 255) & ~(size_t)255));
    float*          h0       = (float*)overlay;                       // reuse after permute
    float*          h1       = h0 + (size_t)n_nodes * HIDDEN;
    (void)ws_size;

    const int TB = 256;
    const int node_blocks = (n_nodes + TB - 1) / TB;
    const int edge_blocks = (int)((n_edges + TB - 1) / TB);
    const int gu_blocks   = (n_nodes + 15) / 16;

    // CSR build (once; reused by both layers)
    hipMemsetAsync(counts, 0, (size_t)(n_nodes + 1) * sizeof(int), stream);
    count_pos_kernel<<<edge_blocks, TB, 0, stream>>>(dst, counts, pos, n_edges);
    scan_kernel<<<1, 1024, 0, stream>>>(counts, offsets, n_nodes);
    scatter_kernel<<<edge_blocks, TB, 0, stream>>>(dst, pos, offsets, eid, n_edges);
    permute_kernel<<<edge_blocks, TB, 0, stream>>>(eid, src, edge_feat, src_perm, ef_perm, n_edges);

    embed_kernel<<<node_blocks, TB, 0, stream>>>(vertex, w_init, h0, n_nodes);

    // layer 1: h0 -> h1
    gather_update_kernel<<<gu_blocks, TB, 0, stream>>>(h0, ef_perm, src_perm, offsets,
                                                       gw, uw, h1, n_nodes);
    // layer 2: h1 -> out
    gather_update_kernel<<<gu_blocks, TB, 0, stream>>>(h1, ef_perm, src_perm, offsets,
                                                       gw, uw, out, n_nodes);
}

// Round 4
// 1055.380 us; speedup vs baseline: 6.3169x; 1.3273x over previous
//
#include <hip/hip_runtime.h>

#define ATOMF 82
#define EDGE_DIM 6
#define HIDDEN 10

__device__ __forceinline__ float lrelu(float x) { return x > 0.f ? x : 0.1f * x; }

__device__ __forceinline__ unsigned int f2bf(float f) {
    unsigned int u = __float_as_uint(f);
    return (u + 0x7fffu + ((u >> 16) & 1u)) >> 16;  // RNE
}
__device__ __forceinline__ float bf2f(unsigned int b) {
    return __uint_as_float(b << 16);
}

// h[node] = lrelu(vertex[node] @ W)   W: [82][10] row-major
__global__ void embed_kernel(const float* __restrict__ vertex,
                             const float* __restrict__ W,
                             float* __restrict__ h, int n_nodes) {
    __shared__ float w[ATOMF * HIDDEN];
    for (int i = threadIdx.x; i < ATOMF * HIDDEN; i += blockDim.x) w[i] = W[i];
    __syncthreads();
    int node = blockIdx.x * blockDim.x + threadIdx.x;
    if (node >= n_nodes) return;
    const float2* v = (const float2*)(vertex + (long)node * ATOMF);  // 328B rows, 8B aligned
    float acc[HIDDEN];
#pragma unroll
    for (int j = 0; j < HIDDEN; j++) acc[j] = 0.f;
#pragma unroll 2
    for (int k2 = 0; k2 < ATOMF / 2; k2++) {
        float2 t = v[k2];
#pragma unroll
        for (int j = 0; j < HIDDEN; j++) acc[j] += t.x * w[(2 * k2) * HIDDEN + j];
#pragma unroll
        for (int j = 0; j < HIDDEN; j++) acc[j] += t.y * w[(2 * k2 + 1) * HIDDEN + j];
    }
    float* out = h + (long)node * HIDDEN;
#pragma unroll
    for (int j = 0; j < HIDDEN; j++) out[j] = lrelu(acc[j]);
}

// per-edge position within its dst bucket + per-node degree; 4 edges/thread
__global__ void count_pos_kernel(const int* __restrict__ dst, int* __restrict__ counts,
                                 unsigned short* __restrict__ pos, long n_edges) {
    long e0 = ((long)blockIdx.x * blockDim.x + threadIdx.x) * 4;
    if (e0 + 3 < n_edges) {
        int4 d = *(const int4*)(dst + e0);
        ushort4 p;
        p.x = (unsigned short)atomicAdd(&counts[d.x], 1);
        p.y = (unsigned short)atomicAdd(&counts[d.y], 1);
        p.z = (unsigned short)atomicAdd(&counts[d.z], 1);
        p.w = (unsigned short)atomicAdd(&counts[d.w], 1);
        *(ushort4*)(pos + e0) = p;
    } else {
        for (long e = e0; e < n_edges; e++)
            pos[e] = (unsigned short)atomicAdd(&counts[dst[e]], 1);
    }
}

// ---- device-wide exclusive scan of counts[0..n-1] -> offsets[0..n] ----
// A: per-block sums (blocks of 1024 over n+1 padded domain)
__global__ __launch_bounds__(1024) void scan_block_sums(const int* __restrict__ counts,
                                                        int* __restrict__ partials, int n) {
    __shared__ int ws[16];
    int i = blockIdx.x * 1024 + threadIdx.x;
    int v = (i < n) ? counts[i] : 0;
    int lane = threadIdx.x & 63, wid = threadIdx.x >> 6;
    int s = v;
#pragma unroll
    for (int off = 32; off > 0; off >>= 1) s += __shfl_down(s, off, 64);
    if (lane == 0) ws[wid] = s;
    __syncthreads();
    if (threadIdx.x == 0) {
        int t = 0;
#pragma unroll
        for (int k = 0; k < 16; k++) t += ws[k];
        partials[blockIdx.x] = t;
    }
}
// B: single-block exclusive scan of partials[0..nb-1] (nb <= 1024)
__global__ __launch_bounds__(1024) void scan_partials(int* __restrict__ partials, int nb) {
    __shared__ int wsum[16];
    int lane = threadIdx.x & 63, wid = threadIdx.x >> 6;
    int v = (threadIdx.x < nb) ? partials[threadIdx.x] : 0;
    int incl = v;
#pragma unroll
    for (int off = 1; off < 64; off <<= 1) {
        int t = __shfl_up(incl, off, 64);
        if (lane >= off) incl += t;
    }
    if (lane == 63) wsum[wid] = incl;
    __syncthreads();
    if (wid == 0 && lane < 16) {
        int wv = wsum[lane];
        int wincl = wv;
#pragma unroll
        for (int off = 1; off < 16; off <<= 1) {
            int t = __shfl_up(wincl, off, 64);
            if (lane >= off) wincl += t;
        }
        wsum[lane] = wincl - wv;
    }
    __syncthreads();
    if (threadIdx.x < nb) partials[threadIdx.x] = wsum[wid] + (incl - v);
}
// C: final — offsets[i] = partials[b] + intra-block exclusive prefix, i in [0, n]
__global__ __launch_bounds__(1024) void scan_final(const int* __restrict__ counts,
                                                   const int* __restrict__ partials,
                                                   int* __restrict__ offsets, int n) {
    __shared__ int wsum[16];
    int i = blockIdx.x * 1024 + threadIdx.x;
    int v = (i < n) ? counts[i] : 0;
    int lane = threadIdx.x & 63, wid = threadIdx.x >> 6;
    int incl = v;
#pragma unroll
    for (int off = 1; off < 64; off <<= 1) {
        int t = __shfl_up(incl, off, 64);
        if (lane >= off) incl += t;
    }
    if (lane == 63) wsum[wid] = incl;
    __syncthreads();
    if (wid == 0 && lane < 16) {
        int wv = wsum[lane];
        int wincl = wv;
#pragma unroll
        for (int off = 1; off < 16; off <<= 1) {
            int t = __shfl_up(wincl, off, 64);
            if (lane >= off) wincl += t;
        }
        wsum[lane] = wincl - wv;
    }
    __syncthreads();
    if (i <= n) offsets[i] = partials[blockIdx.x] + wsum[wid] + (incl - v);
}

// fused scatter+permute: edge-order coalesced reads, one 16B record scatter-write
// rec[offsets[dst[e]] + pos[e]] = {src[e], bf16(ef[e][0..5])}
__global__ void scatter_rec_kernel(const int* __restrict__ src, const int* __restrict__ dst,
                                   const float* __restrict__ ef,
                                   const unsigned short* __restrict__ pos,
                                   const int* __restrict__ offsets,
                                   int4* __restrict__ rec, long n_edges) {
    long e = (long)blockIdx.x * blockDim.x + threadIdx.x;
    if (e >= n_edges) return;
    int d = dst[e];
    int q = offsets[d] + (int)pos[e];
    const float2* er = (const float2*)(ef + e * (long)EDGE_DIM);
    float2 a = er[0], b = er[1], c = er[2];
    int4 r;
    r.x = src[e];
    r.y = (int)(f2bf(a.x) | (f2bf(a.y) << 16));
    r.z = (int)(f2bf(b.x) | (f2bf(b.y) << 16));
    r.w = (int)(f2bf(c.x) | (f2bf(c.y) << 16));
    rec[q] = r;
}

// 16 lanes per dst node: stream 16B CSR records, gather h (L2-resident), fuse update GEMV
__global__ __launch_bounds__(256) void gather_update_kernel(
    const float* __restrict__ h_in, const int4* __restrict__ rec,
    const int* __restrict__ offsets,
    const float* __restrict__ GW, const float* __restrict__ UW,
    float* __restrict__ h_out, int n_nodes) {
    __shared__ float gw[(HIDDEN + EDGE_DIM) * HIDDEN];
    __shared__ float uw[2 * HIDDEN * HIDDEN];
    for (int i = threadIdx.x; i < (HIDDEN + EDGE_DIM) * HIDDEN; i += 256) gw[i] = GW[i];
    for (int i = threadIdx.x; i < 2 * HIDDEN * HIDDEN; i += 256) uw[i] = UW[i];
    __syncthreads();
    int group = threadIdx.x >> 4;  // 16 nodes per block
    int sub = threadIdx.x & 15;
    int node = blockIdx.x * 16 + group;
    if (node >= n_nodes) return;
    int off0 = offsets[node], off1 = offsets[node + 1];
    float acc[HIDDEN];
#pragma unroll
    for (int j = 0; j < HIDDEN; j++) acc[j] = 0.f;
    for (int p = off0 + sub; p < off1; p += 16) {
        int4 r = rec[p];
        int s = r.x;
        float in[HIDDEN + EDGE_DIM];
        const float2* hp = (const float2*)(h_in + (long)s * HIDDEN);
#pragma unroll
        for (int k = 0; k < 5; k++) { float2 t = hp[k]; in[2 * k] = t.x; in[2 * k + 1] = t.y; }
        unsigned int u0 = (unsigned int)r.y, u1 = (unsigned int)r.z, u2 = (unsigned int)r.w;
        in[10] = bf2f(u0 & 0xffffu); in[11] = bf2f(u0 >> 16);
        in[12] = bf2f(u1 & 0xffffu); in[13] = bf2f(u1 >> 16);
        in[14] = bf2f(u2 & 0xffffu); in[15] = bf2f(u2 >> 16);
        float m[HIDDEN];
#pragma unroll
        for (int j = 0; j < HIDDEN; j++) m[j] = 0.f;
#pragma unroll
        for (int k = 0; k < HIDDEN + EDGE_DIM; k++) {
            float x = in[k];
#pragma unroll
            for (int j = 0; j < HIDDEN; j++) m[j] += x * gw[k * HIDDEN + j];
        }
#pragma unroll
        for (int j = 0; j < HIDDEN; j++) acc[j] += lrelu(m[j]);
    }
#pragma unroll
    for (int j = 0; j < HIDDEN; j++) {
#pragma unroll
        for (int d = 8; d > 0; d >>= 1) acc[j] += __shfl_down(acc[j], d, 16);
    }
    if (sub == 0) {
        float in[2 * HIDDEN];
        const float2* hp = (const float2*)(h_in + (long)node * HIDDEN);
#pragma unroll
        for (int k = 0; k < 5; k++) { float2 t = hp[k]; in[2 * k] = t.x; in[2 * k + 1] = t.y; }
#pragma unroll
        for (int j = 0; j < HIDDEN; j++) in[HIDDEN + j] = acc[j];
        float o[HIDDEN];
#pragma unroll
        for (int j = 0; j < HIDDEN; j++) o[j] = 0.f;
#pragma unroll
        for (int k = 0; k < 2 * HIDDEN; k++) {
            float x = in[k];
#pragma unroll
            for (int j = 0; j < HIDDEN; j++) o[j] += x * uw[k * HIDDEN + j];
        }
        float* outp = h_out + (long)node * HIDDEN;
#pragma unroll
        for (int j = 0; j < HIDDEN; j++) outp[j] = lrelu(o[j]);
    }
}

extern "C" void kernel_launch(void* const* d_in, const int* in_sizes, int n_in,
                              void* d_out, int out_size, void* d_ws, size_t ws_size,
                              hipStream_t stream) {
    const float* vertex    = (const float*)d_in[0];
    const float* edge_feat = (const float*)d_in[1];
    const int*   src       = (const int*)d_in[2];
    const int*   dst       = (const int*)d_in[3];
    const float* w_init    = (const float*)d_in[4];
    const float* gw        = (const float*)d_in[5];
    const float* uw        = (const float*)d_in[6];

    const int  n_nodes = in_sizes[0] / ATOMF;
    const long n_edges = (long)in_sizes[2];
    float* out = (float*)d_out;

    // workspace layout (256B-aligned). pos dies after scatter_rec; h0/h1 overlay it.
    char* ws = (char*)d_ws;
    size_t o = 0;
    auto alloc = [&](size_t bytes) { char* p = ws + o; o = (o + bytes + 255) & ~(size_t)255; return p; };
    int*            counts   = (int*)alloc((size_t)(n_nodes + 1) * sizeof(int));
    int*            offsets  = (int*)alloc((size_t)(n_nodes + 1) * sizeof(int));
    int*            partials = (int*)alloc(2048 * sizeof(int));
    int4*           rec      = (int4*)alloc((size_t)n_edges * sizeof(int4));
    size_t ov_bytes = (size_t)n_edges * sizeof(unsigned short);
    size_t h_bytes  = 2 * (size_t)n_nodes * HIDDEN * sizeof(float);
    char*           overlay  = alloc(ov_bytes > h_bytes ? ov_bytes : h_bytes);
    unsigned short* pos      = (unsigned short*)overlay;
    float*          h0       = (float*)overlay;  // reuse after scatter_rec
    float*          h1       = h0 + (size_t)n_nodes * HIDDEN;
    (void)ws_size;

    const int TB = 256;
    const int node_blocks = (n_nodes + TB - 1) / TB;
    const int edge_blocks = (int)((n_edges + TB - 1) / TB);
    const int cp_blocks   = (int)((n_edges / 4 + TB - 1) / TB);
    const int gu_blocks   = (n_nodes + 15) / 16;
    const int scan_blocks = (n_nodes + 1 + 1023) / 1024;  // covers [0, n]

    // CSR build (once; reused by both layers)
    hipMemsetAsync(counts, 0, (size_t)(n_nodes + 1) * sizeof(int), stream);
    count_pos_kernel<<<cp_blocks, TB, 0, stream>>>(dst, counts, pos, n_edges);
    scan_block_sums<<<scan_blocks, 1024, 0, stream>>>(counts, partials, n_nodes);
    scan_partials<<<1, 1024, 0, stream>>>(partials, scan_blocks);
    scan_final<<<scan_blocks, 1024, 0, stream>>>(counts, partials, offsets, n_nodes);
    scatter_rec_kernel<<<edge_blocks, TB, 0, stream>>>(src, dst, edge_feat, pos, offsets,
                                                       rec, n_edges);

    embed_kernel<<<node_blocks, TB, 0, stream>>>(vertex, w_init, h0, n_nodes);

    // layer 1: h0 -> h1
    gather_update_kernel<<<gu_blocks, TB, 0, stream>>>(h0, rec, offsets, gw, uw, h1, n_nodes);
    // layer 2: h1 -> out
    gather_update_kernel<<<gu_blocks, TB, 0, stream>>>(h1, rec, offsets, gw, uw, out, n_nodes);
}

// Round 5
// 916.188 us; speedup vs baseline: 7.2765x; 1.1519x over previous
//
#include <hip/hip_runtime.h>

#define ATOMF 82
#define EDGE_DIM 6
#define HIDDEN 10
#define ZPAD 16  // z row = 10 bf16 + 6 pad = 32 B

__device__ __forceinline__ float lrelu(float x) { return x > 0.f ? x : 0.1f * x; }

__device__ __forceinline__ unsigned int f2bf(float f) {
    unsigned int u = __float_as_uint(f);
    return (u + 0x7fffu + ((u >> 16) & 1u)) >> 16;  // RNE
}
__device__ __forceinline__ float bf2f(unsigned int b) {
    return __uint_as_float(b << 16);
}

// h[node] = lrelu(vertex[node] @ W); z[node] = bf16(h[node] @ GW_h)
__global__ void embed_kernel(const float* __restrict__ vertex,
                             const float* __restrict__ W,
                             const float* __restrict__ GW,
                             float* __restrict__ h, unsigned short* __restrict__ z,
                             int n_nodes) {
    __shared__ float w[ATOMF * HIDDEN];
    __shared__ float gwh[HIDDEN * HIDDEN];
    for (int i = threadIdx.x; i < ATOMF * HIDDEN; i += blockDim.x) w[i] = W[i];
    for (int i = threadIdx.x; i < HIDDEN * HIDDEN; i += blockDim.x) gwh[i] = GW[i];
    __syncthreads();
    int node = blockIdx.x * blockDim.x + threadIdx.x;
    if (node >= n_nodes) return;
    const float2* v = (const float2*)(vertex + (long)node * ATOMF);  // 328B rows, 8B aligned
    float acc[HIDDEN];
#pragma unroll
    for (int j = 0; j < HIDDEN; j++) acc[j] = 0.f;
#pragma unroll 2
    for (int k2 = 0; k2 < ATOMF / 2; k2++) {
        float2 t = v[k2];
#pragma unroll
        for (int j = 0; j < HIDDEN; j++) acc[j] += t.x * w[(2 * k2) * HIDDEN + j];
#pragma unroll
        for (int j = 0; j < HIDDEN; j++) acc[j] += t.y * w[(2 * k2 + 1) * HIDDEN + j];
    }
    float ho[HIDDEN];
    float* out = h + (long)node * HIDDEN;
#pragma unroll
    for (int j = 0; j < HIDDEN; j++) { ho[j] = lrelu(acc[j]); out[j] = ho[j]; }
    float zv[HIDDEN];
#pragma unroll
    for (int j = 0; j < HIDDEN; j++) zv[j] = 0.f;
#pragma unroll
    for (int k = 0; k < HIDDEN; k++) {
        float x = ho[k];
#pragma unroll
        for (int j = 0; j < HIDDEN; j++) zv[j] += x * gwh[k * HIDDEN + j];
    }
    unsigned int* zq = (unsigned int*)(z + (size_t)node * ZPAD);
    int4 pk;
    pk.x = (int)(f2bf(zv[0]) | (f2bf(zv[1]) << 16));
    pk.y = (int)(f2bf(zv[2]) | (f2bf(zv[3]) << 16));
    pk.z = (int)(f2bf(zv[4]) | (f2bf(zv[5]) << 16));
    pk.w = (int)(f2bf(zv[6]) | (f2bf(zv[7]) << 16));
    *(int4*)zq = pk;
    zq[4] = f2bf(zv[8]) | (f2bf(zv[9]) << 16);
}

// per-edge position within its dst bucket + per-node degree; 4 edges/thread
__global__ void count_pos_kernel(const int* __restrict__ dst, int* __restrict__ counts,
                                 unsigned short* __restrict__ pos, long n_edges) {
    long e0 = ((long)blockIdx.x * blockDim.x + threadIdx.x) * 4;
    if (e0 + 3 < n_edges) {
        int4 d = *(const int4*)(dst + e0);
        ushort4 p;
        p.x = (unsigned short)atomicAdd(&counts[d.x], 1);
        p.y = (unsigned short)atomicAdd(&counts[d.y], 1);
        p.z = (unsigned short)atomicAdd(&counts[d.z], 1);
        p.w = (unsigned short)atomicAdd(&counts[d.w], 1);
        *(ushort4*)(pos + e0) = p;
    } else {
        for (long e = e0; e < n_edges; e++)
            pos[e] = (unsigned short)atomicAdd(&counts[dst[e]], 1);
    }
}

// ---- device-wide exclusive scan of counts[0..n-1] -> offsets[0..n] ----
__global__ __launch_bounds__(1024) void scan_block_sums(const int* __restrict__ counts,
                                                        int* __restrict__ partials, int n) {
    __shared__ int ws[16];
    int i = blockIdx.x * 1024 + threadIdx.x;
    int v = (i < n) ? counts[i] : 0;
    int lane = threadIdx.x & 63, wid = threadIdx.x >> 6;
    int s = v;
#pragma unroll
    for (int off = 32; off > 0; off >>= 1) s += __shfl_down(s, off, 64);
    if (lane == 0) ws[wid] = s;
    __syncthreads();
    if (threadIdx.x == 0) {
        int t = 0;
#pragma unroll
        for (int k = 0; k < 16; k++) t += ws[k];
        partials[blockIdx.x] = t;
    }
}
__global__ __launch_bounds__(1024) void scan_partials(int* __restrict__ partials, int nb) {
    __shared__ int wsum[16];
    int lane = threadIdx.x & 63, wid = threadIdx.x >> 6;
    int v = (threadIdx.x < nb) ? partials[threadIdx.x] : 0;
    int incl = v;
#pragma unroll
    for (int off = 1; off < 64; off <<= 1) {
        int t = __shfl_up(incl, off, 64);
        if (lane >= off) incl += t;
    }
    if (lane == 63) wsum[wid] = incl;
    __syncthreads();
    if (wid == 0 && lane < 16) {
        int wv = wsum[lane];
        int wincl = wv;
#pragma unroll
        for (int off = 1; off < 16; off <<= 1) {
            int t = __shfl_up(wincl, off, 64);
            if (lane >= off) wincl += t;
        }
        wsum[lane] = wincl - wv;
    }
    __syncthreads();
    if (threadIdx.x < nb) partials[threadIdx.x] = wsum[wid] + (incl - v);
}
__global__ __launch_bounds__(1024) void scan_final(const int* __restrict__ counts,
                                                   const int* __restrict__ partials,
                                                   int* __restrict__ offsets, int n) {
    __shared__ int wsum[16];
    int i = blockIdx.x * 1024 + threadIdx.x;
    int v = (i < n) ? counts[i] : 0;
    int lane = threadIdx.x & 63, wid = threadIdx.x >> 6;
    int incl = v;
#pragma unroll
    for (int off = 1; off < 64; off <<= 1) {
        int t = __shfl_up(incl, off, 64);
        if (lane >= off) incl += t;
    }
    if (lane == 63) wsum[wid] = incl;
    __syncthreads();
    if (wid == 0 && lane < 16) {
        int wv = wsum[lane];
        int wincl = wv;
#pragma unroll
        for (int off = 1; off < 16; off <<= 1) {
            int t = __shfl_up(wincl, off, 64);
            if (lane >= off) wincl += t;
        }
        wsum[lane] = wincl - wv;
    }
    __syncthreads();
    if (i <= n) offsets[i] = partials[blockIdx.x] + wsum[wid] + (incl - v);
}

// fused scatter+permute: coalesced edge-order reads, one 16B record scatter-write
__global__ void scatter_rec_kernel(const int* __restrict__ src, const int* __restrict__ dst,
                                   const float* __restrict__ ef,
                                   const unsigned short* __restrict__ pos,
                                   const int* __restrict__ offsets,
                                   int4* __restrict__ rec, long n_edges) {
    long e = (long)blockIdx.x * blockDim.x + threadIdx.x;
    if (e >= n_edges) return;
    int d = dst[e];
    int q = offsets[d] + (int)pos[e];
    const float2* er = (const float2*)(ef + e * (long)EDGE_DIM);
    float2 a = er[0], b = er[1], c = er[2];
    int4 r;
    r.x = src[e];
    r.y = (int)(f2bf(a.x) | (f2bf(a.y) << 16));
    r.z = (int)(f2bf(b.x) | (f2bf(b.y) << 16));
    r.w = (int)(f2bf(c.x) | (f2bf(c.y) << 16));
    rec[q] = r;
}

// 16 lanes per dst node: stream CSR records, gather bf16 z (1 sector/edge),
// msg = lrelu(z[src] + ef@GW_e); fused update GEMV + next-layer z epilogue
__global__ __launch_bounds__(256) void gather_update_kernel(
    const float* __restrict__ h_in, const unsigned short* __restrict__ z_in,
    const int4* __restrict__ rec, const int* __restrict__ offsets,
    const float* __restrict__ GW, const float* __restrict__ UW,
    float* __restrict__ h_out, unsigned short* __restrict__ z_out,
    int n_nodes, int write_z) {
    __shared__ float gwh[HIDDEN * HIDDEN];    // GW rows 0..9  (h part)
    __shared__ float gwe[EDGE_DIM * HIDDEN];  // GW rows 10..15 (ef part)
    __shared__ float uw[2 * HIDDEN * HIDDEN];
    for (int i = threadIdx.x; i < HIDDEN * HIDDEN; i += 256) gwh[i] = GW[i];
    for (int i = threadIdx.x; i < EDGE_DIM * HIDDEN; i += 256) gwe[i] = GW[HIDDEN * HIDDEN + i];
    for (int i = threadIdx.x; i < 2 * HIDDEN * HIDDEN; i += 256) uw[i] = UW[i];
    __syncthreads();
    int group = threadIdx.x >> 4;  // 16 nodes per block
    int sub = threadIdx.x & 15;
    int node = blockIdx.x * 16 + group;
    if (node >= n_nodes) return;
    int off0 = offsets[node], off1 = offsets[node + 1];
    float acc[HIDDEN];
#pragma unroll
    for (int j = 0; j < HIDDEN; j++) acc[j] = 0.f;
    int p = off0 + sub;
    int4 r;
    if (p < off1) r = rec[p];
    while (p < off1) {
        int pn = p + 16;
        int4 rn = r;
        if (pn < off1) rn = rec[pn];  // prefetch next record over current z latency
        const int* zq = (const int*)(z_in + (size_t)r.x * ZPAD);
        int4 za = *(const int4*)zq;
        int zb = zq[4];
        float ef[EDGE_DIM];
        unsigned int u0 = (unsigned int)r.y, u1 = (unsigned int)r.z, u2 = (unsigned int)r.w;
        ef[0] = bf2f(u0 & 0xffffu); ef[1] = bf2f(u0 >> 16);
        ef[2] = bf2f(u1 & 0xffffu); ef[3] = bf2f(u1 >> 16);
        ef[4] = bf2f(u2 & 0xffffu); ef[5] = bf2f(u2 >> 16);
        float m[HIDDEN];
#pragma unroll
        for (int j = 0; j < HIDDEN; j++) m[j] = 0.f;
#pragma unroll
        for (int k = 0; k < EDGE_DIM; k++) {
            float x = ef[k];
#pragma unroll
            for (int j = 0; j < HIDDEN; j++) m[j] += x * gwe[k * HIDDEN + j];
        }
        unsigned int z0 = (unsigned int)za.x, z1 = (unsigned int)za.y;
        unsigned int z2 = (unsigned int)za.z, z3 = (unsigned int)za.w, z4 = (unsigned int)zb;
        acc[0] += lrelu(m[0] + bf2f(z0 & 0xffffu));
        acc[1] += lrelu(m[1] + bf2f(z0 >> 16));
        acc[2] += lrelu(m[2] + bf2f(z1 & 0xffffu));
        acc[3] += lrelu(m[3] + bf2f(z1 >> 16));
        acc[4] += lrelu(m[4] + bf2f(z2 & 0xffffu));
        acc[5] += lrelu(m[5] + bf2f(z2 >> 16));
        acc[6] += lrelu(m[6] + bf2f(z3 & 0xffffu));
        acc[7] += lrelu(m[7] + bf2f(z3 >> 16));
        acc[8] += lrelu(m[8] + bf2f(z4 & 0xffffu));
        acc[9] += lrelu(m[9] + bf2f(z4 >> 16));
        r = rn; p = pn;
    }
#pragma unroll
    for (int j = 0; j < HIDDEN; j++) {
#pragma unroll
        for (int d = 8; d > 0; d >>= 1) acc[j] += __shfl_down(acc[j], d, 16);
    }
    if (sub == 0) {
        float in[2 * HIDDEN];
        const float2* hp = (const float2*)(h_in + (long)node * HIDDEN);
#pragma unroll
        for (int k = 0; k < 5; k++) { float2 t = hp[k]; in[2 * k] = t.x; in[2 * k + 1] = t.y; }
#pragma unroll
        for (int j = 0; j < HIDDEN; j++) in[HIDDEN + j] = acc[j];
        float o[HIDDEN];
#pragma unroll
        for (int j = 0; j < HIDDEN; j++) o[j] = 0.f;
#pragma unroll
        for (int k = 0; k < 2 * HIDDEN; k++) {
            float x = in[k];
#pragma unroll
            for (int j = 0; j < HIDDEN; j++) o[j] += x * uw[k * HIDDEN + j];
        }
        float ho[HIDDEN];
        float* outp = h_out + (long)node * HIDDEN;
#pragma unroll
        for (int j = 0; j < HIDDEN; j++) { ho[j] = lrelu(o[j]); outp[j] = ho[j]; }
        if (write_z) {
            float zv[HIDDEN];
#pragma unroll
            for (int j = 0; j < HIDDEN; j++) zv[j] = 0.f;
#pragma unroll
            for (int k = 0; k < HIDDEN; k++) {
                float x = ho[k];
#pragma unroll
                for (int j = 0; j < HIDDEN; j++) zv[j] += x * gwh[k * HIDDEN + j];
            }
            unsigned int* zq = (unsigned int*)(z_out + (size_t)node * ZPAD);
            int4 pk;
            pk.x = (int)(f2bf(zv[0]) | (f2bf(zv[1]) << 16));
            pk.y = (int)(f2bf(zv[2]) | (f2bf(zv[3]) << 16));
            pk.z = (int)(f2bf(zv[4]) | (f2bf(zv[5]) << 16));
            pk.w = (int)(f2bf(zv[6]) | (f2bf(zv[7]) << 16));
            *(int4*)zq = pk;
            zq[4] = f2bf(zv[8]) | (f2bf(zv[9]) << 16);
        }
    }
}

extern "C" void kernel_launch(void* const* d_in, const int* in_sizes, int n_in,
                              void* d_out, int out_size, void* d_ws, size_t ws_size,
                              hipStream_t stream) {
    const float* vertex    = (const float*)d_in[0];
    const float* edge_feat = (const float*)d_in[1];
    const int*   src       = (const int*)d_in[2];
    const int*   dst       = (const int*)d_in[3];
    const float* w_init    = (const float*)d_in[4];
    const float* gw        = (const float*)d_in[5];
    const float* uw        = (const float*)d_in[6];

    const int  n_nodes = in_sizes[0] / ATOMF;
    const long n_edges = (long)in_sizes[2];
    float* out = (float*)d_out;

    // workspace layout (256B-aligned). pos dies after scatter_rec; h/z tables overlay it.
    char* ws = (char*)d_ws;
    size_t o = 0;
    auto alloc = [&](size_t bytes) { char* p = ws + o; o = (o + bytes + 255) & ~(size_t)255; return p; };
    int*  counts   = (int*)alloc((size_t)(n_nodes + 1) * sizeof(int));
    int*  offsets  = (int*)alloc((size_t)(n_nodes + 1) * sizeof(int));
    int*  partials = (int*)alloc(2048 * sizeof(int));
    int4* rec      = (int4*)alloc((size_t)n_edges * sizeof(int4));
    size_t pos_bytes = (size_t)n_edges * sizeof(unsigned short);
    size_t tbl_bytes = (size_t)n_nodes * (2 * HIDDEN * sizeof(float) + 2 * ZPAD * sizeof(unsigned short));
    char* overlay = alloc(pos_bytes > tbl_bytes ? pos_bytes : tbl_bytes);
    unsigned short* pos = (unsigned short*)overlay;
    float*          h0  = (float*)overlay;  // valid after scatter_rec
    float*          h1  = h0 + (size_t)n_nodes * HIDDEN;
    unsigned short* z0  = (unsigned short*)(h1 + (size_t)n_nodes * HIDDEN);
    unsigned short* z1  = z0 + (size_t)n_nodes * ZPAD;
    (void)ws_size;

    const int TB = 256;
    const int node_blocks = (n_nodes + TB - 1) / TB;
    const int edge_blocks = (int)((n_edges + TB - 1) / TB);
    const int cp_blocks   = (int)((n_edges / 4 + TB - 1) / TB);
    const int gu_blocks   = (n_nodes + 15) / 16;
    const int scan_blocks = (n_nodes + 1 + 1023) / 1024;

    // CSR build (once; reused by both layers)
    hipMemsetAsync(counts, 0, (size_t)(n_nodes + 1) * sizeof(int), stream);
    count_pos_kernel<<<cp_blocks, TB, 0, stream>>>(dst, counts, pos, n_edges);
    scan_block_sums<<<scan_blocks, 1024, 0, stream>>>(counts, partials, n_nodes);
    scan_partials<<<1, 1024, 0, stream>>>(partials, scan_blocks);
    scan_final<<<scan_blocks, 1024, 0, stream>>>(counts, partials, offsets, n_nodes);
    scatter_rec_kernel<<<edge_blocks, TB, 0, stream>>>(src, dst, edge_feat, pos, offsets,
                                                       rec, n_edges);

    embed_kernel<<<node_blocks, TB, 0, stream>>>(vertex, w_init, gw, h0, z0, n_nodes);

    // layer 1: (h0,z0) -> (h1,z1)
    gather_update_kernel<<<gu_blocks, TB, 0, stream>>>(h0, z0, rec, offsets, gw, uw,
                                                       h1, z1, n_nodes, 1);
    // layer 2: (h1,z1) -> out (no z needed)
    gather_update_kernel<<<gu_blocks, TB, 0, stream>>>(h1, z1, rec, offsets, gw, uw,
                                                       out, z0, n_nodes, 0);
}